// Round 5
// baseline (403.318 us; speedup 1.0000x reference)
//
#include <hip/hip_runtime.h>
#include <cstdint>

#define NCOLS  696     // 16 + 120 + 560 subsets of size <= 3, bitmask order
#define NGROUP 174     // NCOLS / 4
#define NREC   136     // 16 singles + 120 pairs
#define WPB    4       // waves per block
#define BLOCK  256
#define GRID   2048    // 8 blocks/CU on 256 CUs; 8192 persistent waves
#define ROWS_PER_WAVE 8 // 65536 / 8192

typedef float v4f __attribute__((ext_vector_type(4)));

// Record id: single a -> a ; pair (a<b) -> 16 + b*(b-1)/2 + a.
constexpr int pr(int a, int b) { return 16 + b * (b - 1) / 2 + a; }

// Per-record source operands (lo | hi<<8): rec[r] = selpair(v[hi], v[lo]).
//  single a: (a,a) -> selpair(I_a, I_a) = I_a (tie, beta tie, choose left).
//  pair (a<b): selpair(L=I_b, R=I_a) = reference pairres(a,b).
struct alignas(8) RecSrc { uint16_t d[NREC]; };
constexpr RecSrc make_recs() {
    RecSrc t{};
    for (int a = 0; a < 16; ++a) t.d[a] = (uint16_t)(a | (a << 8));
    int p = 16;
    for (int b = 1; b < 16; ++b)
        for (int a = 0; a < b; ++a)
            t.d[p++] = (uint16_t)(a | (b << 8));
    return t;
}

// Per-column descriptor (Lrec | Rrec<<8): out = selpair(rec[Lrec], rec[Rrec]).
//  single {h}:   L = R = h            (selpair(X,X) == X)
//  pair {j,h}:   L = R = pr(j,h)
//  triple {i,j,h}: L = pr(j,h) (= combo[1:]), R = pr(i,j) (= combo[:-1])
// Emission order generates subsets sorted by bitmask value.
struct alignas(8) ColTbl { uint16_t d[NCOLS]; };
constexpr ColTbl make_cols() {
    ColTbl t{};
    int p = 0;
    for (int h = 0; h < 16; ++h) {
        t.d[p++] = (uint16_t)(h | (h << 8));
        for (int j = 0; j < h; ++j) {
            int pjh = pr(j, h);
            t.d[p++] = (uint16_t)(pjh | (pjh << 8));
            for (int i = 0; i < j; ++i)
                t.d[p++] = (uint16_t)(pr(j, h) | (pr(i, j) << 8));
        }
    }
    return t;
}

__constant__ RecSrc g_recs = make_recs();
__constant__ ColTbl g_cols = make_cols();

// Tie-exact select. cur comparison uses the sum proxy: RN(0.5l+0.5u) =
// 0.5*RN(l+u) exactly (power-of-two scaling), so ==/> are preserved
// bit-for-bit vs the NumPy fp32 reference. Beta path kept in RN form.
__device__ __forceinline__ float2 selpair(float2 L, float2 R) {
    float curL = __fadd_rn(L.x, L.y);
    float curR = __fadd_rn(R.x, R.y);
    float bL = __fadd_rn(__fmul_rn(0.2f, L.x), __fmul_rn(0.8f, L.y));
    float bR = __fadd_rn(__fmul_rn(0.2f, R.x), __fmul_rn(0.8f, R.y));
    bool choose_right = (curL == curR) ? (bL > bR) : (curL > curR);
    return choose_right ? R : L;
}

__device__ __forceinline__ float2 col_compute(const float2* __restrict__ rec,
                                              uint32_t d) {
    float2 L = rec[d & 255u];
    float2 R = rec[(d >> 8) & 255u];
    return selpair(L, R);
}

// Persistent, barrier-free kernel: each wave is self-sufficient (loads its own
// row, builds its own rec table in its own LDS slice, emits its row). All LDS
// producer->consumer deps are same-wave: the in-order DS pipe + compiler
// lgkmcnt waits order them — no __syncthreads (and thus no vmcnt(0) drains)
// anywhere, so stores from row i stay in flight through row i+1's compute.
__global__ __launch_bounds__(BLOCK) void minint_kernel(
    const float* __restrict__ xl, const float* __restrict__ xu,
    float* __restrict__ out, int batch)
{
    __shared__ float2 vals[WPB][16];
    __shared__ float2 recs[WPB][NREC];
    const int t    = threadIdx.x;
    const int w    = t >> 6;
    const int lane = t & 63;
    const int wgid = blockIdx.x * WPB + w;

    float2* v   = vals[w];
    float2* rec = recs[w];
    const ushort4* cols = (const ushort4*)g_cols.d;

    for (int it = 0; it < ROWS_PER_WAVE; ++it) {
        const int row = wgid * ROWS_PER_WAVE + it;   // 8 consecutive rows/wave
        if (row >= batch) break;

        // Load this wave's row: lanes 0..15 -> xl line, lanes 16..31 -> xu line
        // (2 cachelines, one coalesced instruction). Same-wave LDS write,
        // conflict-free banks (even banks for .x, odd for .y).
        if (lane < 32) {
            const float* src = (lane < 16) ? (xl + (size_t)row * 16 + lane)
                                           : (xu + (size_t)row * 16 + (lane - 16));
            ((float*)v)[(lane & 15) * 2 + (lane >> 4)] = *src;
        }

        // Build the 136 single/pair records (same-wave produce->consume).
        #pragma unroll
        for (int m = 0; m < 3; ++m) {
            int r = lane + 64 * m;
            if (r < NREC) {
                uint32_t s = g_recs.d[r];
                float2 lo = v[s & 15u];
                float2 hi = v[(s >> 8) & 15u];
                rec[r] = selpair(hi, lo);
            }
        }

        float* outl = out + (size_t)row * NCOLS;
        float* outu = out + (size_t)batch * NCOLS + (size_t)row * NCOLS;

        // 174 groups of 4 columns; lane g writes columns [4g,4g+4) of both
        // halves as float4 (1 KB contiguous per store instruction per wave).
        #pragma unroll
        for (int k = 0; k < 3; ++k) {
            int g = lane + 64 * k;
            if (g < NGROUP) {
                ushort4 d4 = cols[g];
                float2 c0 = col_compute(rec, d4.x);
                float2 c1 = col_compute(rec, d4.y);
                float2 c2 = col_compute(rec, d4.z);
                float2 c3 = col_compute(rec, d4.w);
                v4f rl = { c0.x, c1.x, c2.x, c3.x };
                v4f ru = { c0.y, c1.y, c2.y, c3.y };
                __builtin_nontemporal_store(rl, (v4f*)(outl + 4 * g));
                __builtin_nontemporal_store(ru, (v4f*)(outu + 4 * g));
            }
        }
        // Next iteration's LDS writes are ordered after this row's LDS reads
        // by the per-wave in-order DS pipe; no barrier needed.
    }
}

extern "C" void kernel_launch(void* const* d_in, const int* in_sizes, int n_in,
                              void* d_out, int out_size, void* d_ws, size_t ws_size,
                              hipStream_t stream) {
    const float* xl = (const float*)d_in[0];
    const float* xu = (const float*)d_in[1];
    float* out = (float*)d_out;
    const int batch = in_sizes[0] / 16;          // 65536
    minint_kernel<<<GRID, BLOCK, 0, stream>>>(xl, xu, out, batch);
}